// Round 1
// baseline (533.534 us; speedup 1.0000x reference)
//
#include <hip/hip_runtime.h>
#include <math.h>

#define NEG_SLOPE 0.2f
#define N_NODES 50000
#define NREP 8   // one denom replica per XCD (MI355X has 8 XCDs; blockIdx round-robins)

__global__ __launch_bounds__(256) void k_zero(float* __restrict__ p, int n) {
    int i = blockIdx.x * blockDim.x + threadIdx.x;
    if (i < n) p[i] = 0.0f;
}

// Half-wave (32 lanes) per edge: lane loads one float4 of x (16 B/lane,
// 1024 B contiguous per wave across its 2 edges), xor-shuffle reduce within
// the 32-lane half. Sub-lane 0: bias + LeakyReLU + exp (no max-shift needed:
// latent ~ N(0,1), exp bounded, softmax is shift-invariant), store e_v,
// then ONE fp32 HW atomic into the XCD-local denom replica:
// replica r = blockIdx & 7 keeps the atomic's cache line resident in this
// XCD's L2 (device-scope atomics to a line shared by 8 XCDs ping-pong
// through the fabric; replication makes them L2-local).
__global__ __launch_bounds__(256) void k_main(
    const float* __restrict__ x, const float* __restrict__ W,
    const float* __restrict__ b, const int* __restrict__ index,
    float* __restrict__ out, float* __restrict__ rep, int E)
{
    const int tid  = threadIdx.x;
    const int lane = tid & 63;
    const int sub  = lane & 31;
    const int half = lane >> 5;
    const int wave = tid >> 6;
    const int e = blockIdx.x * 8 + wave * 2 + half;
    if (e >= E) return;

    const float4 w4 = ((const float4*)W)[sub];                   // 512 B, L1-hot
    const float4 v  = ((const float4*)x)[(size_t)e * 32 + sub];  // coalesced

    float dot = v.x * w4.x + v.y * w4.y + v.z * w4.z + v.w * w4.w;
    #pragma unroll
    for (int m = 16; m >= 1; m >>= 1)
        dot += __shfl_xor(dot, m, 64);

    if (sub == 0) {
        float val = dot + b[0];
        val = (val >= 0.0f) ? val : NEG_SLOPE * val;
        float ev = __expf(val);          // bounded, no overflow
        out[e] = ev;
        const int r = blockIdx.x & (NREP - 1);
        unsafeAtomicAdd(&rep[(size_t)r * N_NODES + index[e]], ev);
    }
}

// Fold the 8 replicas into the final denominator (coalesced strided reads).
__global__ __launch_bounds__(256) void k_sum(
    const float* __restrict__ rep, float* __restrict__ total)
{
    int i = blockIdx.x * blockDim.x + threadIdx.x;
    if (i < N_NODES) {
        float s = 0.0f;
        #pragma unroll
        for (int r = 0; r < NREP; ++r) s += rep[(size_t)r * N_NODES + i];
        total[i] = s;
    }
}

// 4 edges per thread, float4/int4 vectorized; denom gathers are L2-resident.
__global__ __launch_bounds__(256) void k_div(
    float* __restrict__ out, const int* __restrict__ index,
    const float* __restrict__ denom, int E)
{
    int q = blockIdx.x * blockDim.x + threadIdx.x;
    int base = q * 4;
    if (base + 3 < E) {
        float4 o  = ((float4*)out)[q];
        int4  idx = ((const int4*)index)[q];
        o.x /= denom[idx.x];
        o.y /= denom[idx.y];
        o.z /= denom[idx.z];
        o.w /= denom[idx.w];
        ((float4*)out)[q] = o;
    } else if (base < E) {
        for (int e = base; e < E; ++e) out[e] = out[e] / denom[index[e]];
    }
}

extern "C" void kernel_launch(void* const* d_in, const int* in_sizes, int n_in,
                              void* d_out, int out_size, void* d_ws, size_t ws_size,
                              hipStream_t stream) {
    const float* x     = (const float*)d_in[0];
    const float* W     = (const float*)d_in[1];
    const float* b     = (const float*)d_in[2];
    const int*   index = (const int*)d_in[3];
    float*       out   = (float*)d_out;
    const int E = in_sizes[3];

    float* rep   = (float*)d_ws;                       // NREP * N_NODES floats
    float* denom = rep + (size_t)NREP * N_NODES;       // N_NODES floats

    const int nz = NREP * N_NODES;
    k_zero<<<(nz + 255) / 256, 256, 0, stream>>>(rep, nz);
    k_main<<<(E + 7) / 8, 256, 0, stream>>>(x, W, b, index, out, rep, E);
    k_sum<<<(N_NODES + 255) / 256, 256, 0, stream>>>(rep, denom);
    k_div<<<((E + 3) / 4 + 255) / 256, 256, 0, stream>>>(out, index, denom, E);
}